// Round 4
// baseline (433.500 us; speedup 1.0000x reference)
//
#include <hip/hip_runtime.h>

typedef __attribute__((ext_vector_type(8))) short short8;
typedef __attribute__((ext_vector_type(4))) short s4v;
typedef __attribute__((ext_vector_type(4))) float floatx4;

#define SPOS 16384

// round-to-nearest-even fp32 -> bf16 bits
__device__ __forceinline__ unsigned short f2bf(float f) {
    unsigned u = __float_as_uint(f);
    u += 0x7fffu + ((u >> 16) & 1u);
    return (unsigned short)(u >> 16);
}

// Branchless bit-twiddle posit quantizer (verified equivalent of the 128
// sequential where-passes; see R1/R2 derivation comments).
__device__ __forceinline__ float posit_q(float x) {
    unsigned xu  = __float_as_uint(x);
    unsigned sgn = xu & 0x80000000u;
    unsigned au  = xu & 0x7fffffffu;
    unsigned m   = au & 0x007fffffu;
    unsigned r   = (au + 0x00080000u) & 0xfff00000u;
    bool bdry = (m & 0x000fffffu) == 0x00080000u;
    unsigned res;
    if (au >= 0x3f800000u) {                      // |x| >= 1
        res = r;
        if (m > 0x00700000u && m < 0x00780000u && au < 0x47700000u)
            res = (au & 0xff800000u) + 0x00800000u;   // -> 2^(E+1)
        if ((bdry && m != 0x00780000u) || au >= 0x47780000u)
            res = au;                              // boundaries & clamp unchanged
    } else {                                       // |x| < 1
        res = (m <= 0x00080000u || m >= 0x00780000u || bdry) ? au : r;
        if (au < 0x37880000u) res = au ? 0x37800000u : 0u;  // -> 2^-16 (0 stays 0)
    }
    return __uint_as_float(sgn | res);
}

// Same, for z >= 0 (post-ReLU) — sign handling dropped, bit-identical result.
__device__ __forceinline__ float posit_q_pos(float z) {
    unsigned au  = __float_as_uint(z);
    unsigned m   = au & 0x007fffffu;
    unsigned r   = (au + 0x00080000u) & 0xfff00000u;
    bool bdry = (m & 0x000fffffu) == 0x00080000u;
    unsigned res;
    if (au >= 0x3f800000u) {
        res = r;
        if (m > 0x00700000u && m < 0x00780000u && au < 0x47700000u)
            res = (au & 0xff800000u) + 0x00800000u;
        if ((bdry && m != 0x00780000u) || au >= 0x47780000u)
            res = au;
    } else {
        res = (m <= 0x00080000u || m >= 0x00780000u || bdry) ? au : r;
        if (au < 0x37880000u) res = au ? 0x37800000u : 0u;
    }
    return __uint_as_float(res);
}

// quantize weights to bf16, fold conv bias + BN into per-channel scale/bias
__global__ __launch_bounds__(256) void prep_kernel(
    const float* __restrict__ w1, const float* __restrict__ w2,
    const float* __restrict__ b1, const float* __restrict__ g1,
    const float* __restrict__ be1, const float* __restrict__ m1,
    const float* __restrict__ v1,
    const float* __restrict__ b2, const float* __restrict__ g2,
    const float* __restrict__ be2, const float* __restrict__ m2,
    const float* __restrict__ v2,
    unsigned short* __restrict__ w1q, unsigned short* __restrict__ w2q,
    float* __restrict__ cst)
{
    int i = blockIdx.x * 256 + threadIdx.x;
    if (i < 65536) {
        w1q[i] = f2bf(posit_q(w1[i]));
        w2q[i] = f2bf(posit_q(w2[i]));
        if (i < 256) {
            float inv1 = g1[i] / sqrtf(v1[i] + 1e-5f);
            cst[i]       = inv1;
            cst[256 + i] = fmaf(b1[i], inv1, be1[i] - m1[i] * inv1);
            float inv2 = g2[i] / sqrtf(v2[i] + 1e-5f);
            cst[512 + i] = inv2;
            cst[768 + i] = fmaf(b2[i], inv2, be2[i] - m2[i] * inv2);
        }
    }
}

// q layout: 32 rows (p) x 32 column-blocks of 8 bf16, XOR-swizzled:
// block cb stored at physical block (cb ^ p) -> all LDS ops bank-minimal.
__device__ __forceinline__ int qidx(int p, int cb) {
    return p * 256 + (((cb ^ p) & 31) << 3);
}

// One block: 32 positions x all 256 channels; both GEMMs fused through LDS.
// LDS = 16 KB (q) + 4 KB (xs) = 20480 B; target 5 blocks/CU (20 waves).
__global__ __launch_bounds__(256, 5) void fused_kernel(
    const float* __restrict__ x,
    const unsigned short* __restrict__ w1q,
    const unsigned short* __restrict__ w2q,
    const float* __restrict__ cst,
    float* __restrict__ out)
{
    __shared__ alignas(16) unsigned short q[32 * 256];  // 16 KB, swizzled
    __shared__ alignas(16) float xs[4 * 256];           // 4 KB, wave-private strips

    const int b  = blockIdx.x;          // 4096 blocks
    const int n  = b >> 9;
    const int s0 = (b & 511) << 5;
    const float* xb = x   + (size_t)n * (256 * SPOS) + s0;
    float*       ob = out + (size_t)n * (256 * SPOS) + s0;

    const int t    = threadIdx.x;
    const int lane = t & 63;
    const int w    = t >> 6;            // wave id 0..3
    const int quad = lane >> 4;
    const int l15  = lane & 15;

    // ---- Phase 1 (no barriers): wave w owns channels 64w..64w+63, 32 pos.
    // 8 rounds x 8 channels. xs strip wave-private, XOR-swizzled so the
    // float4 writes and the b32 column reads are bank-minimal.
    {
        const int row  = lane >> 3;     // 0..7 channel-within-round (load)
        const int g    = lane & 7;      // float4 group along p (load)
        const int p    = lane & 31;     // position (quantize)
        const int half = lane >> 5;     // 0/1 -> channels 4h..4h+3 (quantize)
        float* xsw = xs + w * 256;
        const float* src0 = xb + (size_t)(64 * w + row) * SPOS + 4 * g;
        #pragma unroll
        for (int r = 0; r < 8; ++r) {
            const float4 v = *(const float4*)(src0 + (size_t)(8 * r) * SPOS);
            // element p of row cl lives at dword cl*32 + (((p&28)^(4cl)) | (p&3))
            *(float4*)&xsw[row * 32 + ((4 * g) ^ (4 * row))] = v;
            s4v pk;
            #pragma unroll
            for (int j = 0; j < 4; ++j) {
                const int cl = 4 * half + j;
                pk[j] = (short)f2bf(posit_q(
                    xsw[cl * 32 + (((p & 28) ^ (4 * cl)) | (p & 3))]));
            }
            *(s4v*)&q[qidx(p, 8 * w + r) + 4 * half] = pk;
        }
    }
    __syncthreads();    // q fully populated

    const int mbase = w * 64;
    floatx4 acc[4][2];
    #pragma unroll
    for (int i = 0; i < 4; ++i)
        #pragma unroll
        for (int jj = 0; jj < 2; ++jj)
            acc[i][jj] = (floatx4)0.0f;

    // ---- GEMM1: A = W1q (global, L2-hot), B = q ----
    #pragma unroll
    for (int kk = 0; kk < 256; kk += 32) {
        short8 af[4], bf[2];
        #pragma unroll
        for (int i = 0; i < 4; ++i)
            af[i] = *(const short8*)&w1q[(size_t)(mbase + 16 * i + l15) * 256 + kk + quad * 8];
        #pragma unroll
        for (int jj = 0; jj < 2; ++jj)
            bf[jj] = *(const short8*)&q[qidx(16 * jj + l15, (kk >> 3) + quad)];
        #pragma unroll
        for (int i = 0; i < 4; ++i)
            #pragma unroll
            for (int jj = 0; jj < 2; ++jj)
                acc[i][jj] = __builtin_amdgcn_mfma_f32_16x16x32_bf16(af[i], bf[jj], acc[i][jj], 0, 0, 0);
    }
    __syncthreads();   // all waves done reading q before overwrite

    // ---- Epilogue 1: BN1 + ReLU + posit_q -> bf16 back into q[p][m] ----
    {
        const float* sc1 = cst;
        const float* bi1 = cst + 256;
        #pragma unroll
        for (int i = 0; i < 4; ++i) {
            const int m0 = mbase + 16 * i + quad * 4;
            float sc[4], bi[4];
            #pragma unroll
            for (int r = 0; r < 4; ++r) { sc[r] = sc1[m0 + r]; bi[r] = bi1[m0 + r]; }
            #pragma unroll
            for (int jj = 0; jj < 2; ++jj) {
                const int p = 16 * jj + l15;
                s4v h;
                #pragma unroll
                for (int r = 0; r < 4; ++r) {
                    float z = fmaf(acc[i][jj][r], sc[r], bi[r]);
                    z = fmaxf(z, 0.0f);
                    h[r] = (short)f2bf(posit_q_pos(z));
                }
                *(s4v*)&q[qidx(p, m0 >> 3) + (m0 & 7)] = h;
            }
        }
    }
    __syncthreads();

    // ---- GEMM2: A = W2q, B = q (quantized z1) ----
    #pragma unroll
    for (int i = 0; i < 4; ++i)
        #pragma unroll
        for (int jj = 0; jj < 2; ++jj)
            acc[i][jj] = (floatx4)0.0f;

    #pragma unroll
    for (int kk = 0; kk < 256; kk += 32) {
        short8 af[4], bf[2];
        #pragma unroll
        for (int i = 0; i < 4; ++i)
            af[i] = *(const short8*)&w2q[(size_t)(mbase + 16 * i + l15) * 256 + kk + quad * 8];
        #pragma unroll
        for (int jj = 0; jj < 2; ++jj)
            bf[jj] = *(const short8*)&q[qidx(16 * jj + l15, (kk >> 3) + quad)];
        #pragma unroll
        for (int i = 0; i < 4; ++i)
            #pragma unroll
            for (int jj = 0; jj < 2; ++jj)
                acc[i][jj] = __builtin_amdgcn_mfma_f32_16x16x32_bf16(af[i], bf[jj], acc[i][jj], 0, 0, 0);
    }

    // ---- Epilogue 2: BN2 + residual + ReLU -> out ----
    {
        const float* sc2 = cst + 512;
        const float* bi2 = cst + 768;
        #pragma unroll
        for (int i = 0; i < 4; ++i) {
            const int m0 = mbase + 16 * i + quad * 4;
            float sc[4], bi[4];
            #pragma unroll
            for (int r = 0; r < 4; ++r) { sc[r] = sc2[m0 + r]; bi[r] = bi2[m0 + r]; }
            #pragma unroll
            for (int jj = 0; jj < 2; ++jj) {
                const int p = 16 * jj + l15;
                #pragma unroll
                for (int r = 0; r < 4; ++r) {
                    const size_t off = (size_t)(m0 + r) * SPOS + p;
                    float v = fmaf(acc[i][jj][r], sc[r], bi[r]);
                    v += xb[off];                  // residual re-read
                    ob[off] = fmaxf(v, 0.0f);
                }
            }
        }
    }
}

extern "C" void kernel_launch(void* const* d_in, const int* in_sizes, int n_in,
                              void* d_out, int out_size, void* d_ws, size_t ws_size,
                              hipStream_t stream) {
    const float* x   = (const float*)d_in[0];
    const float* w1  = (const float*)d_in[1];
    const float* b1  = (const float*)d_in[2];
    const float* g1  = (const float*)d_in[3];
    const float* be1 = (const float*)d_in[4];
    const float* m1  = (const float*)d_in[5];
    const float* v1  = (const float*)d_in[6];
    const float* w2  = (const float*)d_in[7];
    const float* b2  = (const float*)d_in[8];
    const float* g2  = (const float*)d_in[9];
    const float* be2 = (const float*)d_in[10];
    const float* m2  = (const float*)d_in[11];
    const float* v2  = (const float*)d_in[12];

    unsigned short* w1q = (unsigned short*)d_ws;
    unsigned short* w2q = w1q + 65536;
    float* cst = (float*)(w2q + 65536);   // scale1|bias1|scale2|bias2

    prep_kernel<<<256, 256, 0, stream>>>(w1, w2, b1, g1, be1, m1, v1,
                                         b2, g2, be2, m2, v2, w1q, w2q, cst);
    fused_kernel<<<4096, 256, 0, stream>>>(x, w1q, w2q, cst, (float*)d_out);
}

// Round 5
// 343.246 us; speedup vs baseline: 1.2629x; 1.2629x over previous
//
#include <hip/hip_runtime.h>

typedef __attribute__((ext_vector_type(8))) short short8;
typedef __attribute__((ext_vector_type(4))) short s4v;
typedef __attribute__((ext_vector_type(4))) float floatx4;

#define SPOS 16384

// round-to-nearest-even fp32 -> bf16 bits
__device__ __forceinline__ unsigned short f2bf(float f) {
    unsigned u = __float_as_uint(f);
    u += 0x7fffu + ((u >> 16) & 1u);
    return (unsigned short)(u >> 16);
}

// Branchless bit-twiddle posit quantizer (verified equivalent of the 128
// sequential where-passes; see R1/R2 derivation comments).
__device__ __forceinline__ float posit_q(float x) {
    unsigned xu  = __float_as_uint(x);
    unsigned sgn = xu & 0x80000000u;
    unsigned au  = xu & 0x7fffffffu;
    unsigned m   = au & 0x007fffffu;
    unsigned r   = (au + 0x00080000u) & 0xfff00000u;
    bool bdry = (m & 0x000fffffu) == 0x00080000u;
    unsigned res;
    if (au >= 0x3f800000u) {                      // |x| >= 1
        res = r;
        if (m > 0x00700000u && m < 0x00780000u && au < 0x47700000u)
            res = (au & 0xff800000u) + 0x00800000u;   // -> 2^(E+1)
        if ((bdry && m != 0x00780000u) || au >= 0x47780000u)
            res = au;                              // boundaries & clamp unchanged
    } else {                                       // |x| < 1
        res = (m <= 0x00080000u || m >= 0x00780000u || bdry) ? au : r;
        if (au < 0x37880000u) res = au ? 0x37800000u : 0u;  // -> 2^-16 (0 stays 0)
    }
    return __uint_as_float(sgn | res);
}

// Same, for z >= 0 (post-ReLU) — sign handling dropped, bit-identical result.
__device__ __forceinline__ float posit_q_pos(float z) {
    unsigned au  = __float_as_uint(z);
    unsigned m   = au & 0x007fffffu;
    unsigned r   = (au + 0x00080000u) & 0xfff00000u;
    bool bdry = (m & 0x000fffffu) == 0x00080000u;
    unsigned res;
    if (au >= 0x3f800000u) {
        res = r;
        if (m > 0x00700000u && m < 0x00780000u && au < 0x47700000u)
            res = (au & 0xff800000u) + 0x00800000u;
        if ((bdry && m != 0x00780000u) || au >= 0x47780000u)
            res = au;
    } else {
        res = (m <= 0x00080000u || m >= 0x00780000u || bdry) ? au : r;
        if (au < 0x37880000u) res = au ? 0x37800000u : 0u;
    }
    return __uint_as_float(res);
}

// Quantize weights to bf16 in MFMA-FRAGMENT-PACKED order + fold BN constants.
// Packed layout: i = G*4096 + kb*512 + lane*8 + j  (G=row-group of 16, kb=K-block
// of 32, lane=wave lane, j=0..7) holds W[16G + (lane&15)][32kb + 8*(lane>>4) + j].
// => the K-loop af load is base + lane*16B: one contiguous 1KB wave transaction.
__global__ __launch_bounds__(256) void prep_kernel(
    const float* __restrict__ w1, const float* __restrict__ w2,
    const float* __restrict__ b1, const float* __restrict__ g1,
    const float* __restrict__ be1, const float* __restrict__ m1,
    const float* __restrict__ v1,
    const float* __restrict__ b2, const float* __restrict__ g2,
    const float* __restrict__ be2, const float* __restrict__ m2,
    const float* __restrict__ v2,
    unsigned short* __restrict__ w1p, unsigned short* __restrict__ w2p,
    float* __restrict__ cst)
{
    int i = blockIdx.x * 256 + threadIdx.x;
    if (i < 65536) {
        const int j    = i & 7;
        const int lane = (i >> 3) & 63;
        const int kb   = (i >> 9) & 7;
        const int G    = i >> 12;
        const int row  = 16 * G + (lane & 15);
        const int k    = 32 * kb + 8 * (lane >> 4) + j;
        w1p[i] = f2bf(posit_q(w1[row * 256 + k]));
        w2p[i] = f2bf(posit_q(w2[row * 256 + k]));
        if (i < 256) {
            float inv1 = g1[i] / sqrtf(v1[i] + 1e-5f);
            cst[i]       = inv1;
            cst[256 + i] = fmaf(b1[i], inv1, be1[i] - m1[i] * inv1);
            float inv2 = g2[i] / sqrtf(v2[i] + 1e-5f);
            cst[512 + i] = inv2;
            cst[768 + i] = fmaf(b2[i], inv2, be2[i] - m2[i] * inv2);
        }
    }
}

// q layout: 64 rows (p) x 32 column-blocks of 8 bf16, XOR-swizzled:
// block cb stored at physical block (cb ^ (p & 31)) -> all LDS ops bank-minimal.
__device__ __forceinline__ int qidx(int p, int cb) {
    return p * 256 + ((cb ^ (p & 31)) << 3);
}

// One block: 64 positions x all 256 channels; both GEMMs fused through LDS.
// LDS = 32 KB (q) + 16 KB (xs ping-pong) = 49152 B -> 3 blocks/CU;
// launch_bounds(256,3) gives the allocator ~170 regs for deep load pipelining.
__global__ __launch_bounds__(256, 3) void fused_kernel(
    const float* __restrict__ x,
    const unsigned short* __restrict__ w1p,
    const unsigned short* __restrict__ w2p,
    const float* __restrict__ cst,
    float* __restrict__ out)
{
    __shared__ alignas(16) unsigned short q[64 * 256];  // 32 KB, swizzled
    __shared__ alignas(16) float xs[4 * 1024];          // 16 KB, wave-private ping-pong

    const int b  = blockIdx.x;          // 2048 blocks
    const int n  = b >> 8;
    const int s0 = (b & 255) << 6;
    const float* xb = x   + (size_t)n * (256 * SPOS) + s0;
    float*       ob = out + (size_t)n * (256 * SPOS) + s0;

    const int t    = threadIdx.x;
    const int lane = t & 63;
    const int w    = t >> 6;            // wave id 0..3
    const int quad = lane >> 4;
    const int l15  = lane & 15;

    // ---- Phase 1 (no barriers): wave w owns channels 64w..64w+63.
    // All 16 float4 loads issued up front (in-flight under the 3-wave reg cap),
    // then 8 quantize rounds through a ping-pong xs strip.
    {
        const int g  = lane & 15;       // float4 group along p
        const int co = lane >> 4;       // 0..3
        float* xsw = xs + w * 1024;
        const float* src0 = xb + (size_t)(64 * w + co) * SPOS + 4 * g;
        float4 v[16];
        #pragma unroll
        for (int r = 0; r < 8; ++r) {
            v[2 * r]     = *(const float4*)(src0 + (size_t)(8 * r) * SPOS);
            v[2 * r + 1] = *(const float4*)(src0 + (size_t)(8 * r + 4) * SPOS);
        }
        #pragma unroll
        for (int r = 0; r < 8; ++r) {
            float* xr = xsw + (r & 1) * 512;
            // element p of channel-row cl lives at dword cl*64 + (p ^ 4*cl)
            *(float4*)&xr[co * 64 + ((4 * g) ^ (4 * co))]             = v[2 * r];
            *(float4*)&xr[(co + 4) * 64 + ((4 * g) ^ (4 * (co + 4)))] = v[2 * r + 1];
            short8 pk;
            #pragma unroll
            for (int c8 = 0; c8 < 8; ++c8)
                pk[c8] = (short)f2bf(posit_q(xr[c8 * 64 + (lane ^ (4 * c8))]));
            *(short8*)&q[qidx(lane, 8 * w + r)] = pk;   // cb = (64w+8r)/8
        }
    }
    __syncthreads();    // q fully populated

    floatx4 acc[4][4];
    #pragma unroll
    for (int i = 0; i < 4; ++i)
        #pragma unroll
        for (int jj = 0; jj < 4; ++jj)
            acc[i][jj] = (floatx4)0.0f;

    // ---- GEMM1: A = W1p (packed, coalesced, L2-hot), B = q ----
    #pragma unroll
    for (int kk = 0; kk < 256; kk += 32) {
        short8 af[4], bf[4];
        #pragma unroll
        for (int i = 0; i < 4; ++i)
            af[i] = *(const short8*)&w1p[(((w * 4 + i) * 8 + (kk >> 5)) * 64 + lane) * 8];
        #pragma unroll
        for (int jj = 0; jj < 4; ++jj)
            bf[jj] = *(const short8*)&q[qidx(16 * jj + l15, (kk >> 3) + quad)];
        #pragma unroll
        for (int i = 0; i < 4; ++i)
            #pragma unroll
            for (int jj = 0; jj < 4; ++jj)
                acc[i][jj] = __builtin_amdgcn_mfma_f32_16x16x32_bf16(af[i], bf[jj], acc[i][jj], 0, 0, 0);
    }

    // Prefetch GEMM2's first af set; L2 latency hides under epilogue-1 VALU.
    short8 af20[4];
    #pragma unroll
    for (int i = 0; i < 4; ++i)
        af20[i] = *(const short8*)&w2p[(((w * 4 + i) * 8 + 0) * 64 + lane) * 8];

    __syncthreads();   // all waves done reading q before overwrite

    const int mbase = w * 64;

    // ---- Epilogue 1: BN1 + ReLU + posit_q -> bf16 back into q[p][m] ----
    {
        const float* sc1 = cst;
        const float* bi1 = cst + 256;
        #pragma unroll
        for (int i = 0; i < 4; ++i) {
            const int m0 = mbase + 16 * i + quad * 4;
            float sc[4], bi[4];
            #pragma unroll
            for (int r = 0; r < 4; ++r) { sc[r] = sc1[m0 + r]; bi[r] = bi1[m0 + r]; }
            #pragma unroll
            for (int jj = 0; jj < 4; ++jj) {
                const int p = 16 * jj + l15;
                s4v h;
                #pragma unroll
                for (int r = 0; r < 4; ++r) {
                    float z = fmaf(acc[i][jj][r], sc[r], bi[r]);
                    z = fmaxf(z, 0.0f);
                    h[r] = (short)f2bf(posit_q_pos(z));
                }
                *(s4v*)&q[qidx(p, m0 >> 3) + (m0 & 7)] = h;
            }
        }
    }
    __syncthreads();

    // ---- GEMM2: A = W2p (packed), B = q (quantized z1) ----
    #pragma unroll
    for (int i = 0; i < 4; ++i)
        #pragma unroll
        for (int jj = 0; jj < 4; ++jj)
            acc[i][jj] = (floatx4)0.0f;

    #pragma unroll
    for (int kk = 0; kk < 256; kk += 32) {
        short8 af[4], bf[4];
        #pragma unroll
        for (int i = 0; i < 4; ++i)
            af[i] = (kk == 0) ? af20[i]
                  : *(const short8*)&w2p[(((w * 4 + i) * 8 + (kk >> 5)) * 64 + lane) * 8];
        #pragma unroll
        for (int jj = 0; jj < 4; ++jj)
            bf[jj] = *(const short8*)&q[qidx(16 * jj + l15, (kk >> 3) + quad)];
        #pragma unroll
        for (int i = 0; i < 4; ++i)
            #pragma unroll
            for (int jj = 0; jj < 4; ++jj)
                acc[i][jj] = __builtin_amdgcn_mfma_f32_16x16x32_bf16(af[i], bf[jj], acc[i][jj], 0, 0, 0);
    }

    // ---- Epilogue 2: BN2 + residual + ReLU -> out ----
    {
        const float* sc2 = cst + 512;
        const float* bi2 = cst + 768;
        #pragma unroll
        for (int i = 0; i < 4; ++i) {
            const int m0 = mbase + 16 * i + quad * 4;
            float sc[4], bi[4];
            #pragma unroll
            for (int r = 0; r < 4; ++r) { sc[r] = sc2[m0 + r]; bi[r] = bi2[m0 + r]; }
            #pragma unroll
            for (int jj = 0; jj < 4; ++jj) {
                const int p = 16 * jj + l15;
                #pragma unroll
                for (int r = 0; r < 4; ++r) {
                    const size_t off = (size_t)(m0 + r) * SPOS + p;
                    float v = fmaf(acc[i][jj][r], sc[r], bi[r]);
                    v += xb[off];                  // residual re-read (L2-hot)
                    ob[off] = fmaxf(v, 0.0f);
                }
            }
        }
    }
}

extern "C" void kernel_launch(void* const* d_in, const int* in_sizes, int n_in,
                              void* d_out, int out_size, void* d_ws, size_t ws_size,
                              hipStream_t stream) {
    const float* x   = (const float*)d_in[0];
    const float* w1  = (const float*)d_in[1];
    const float* b1  = (const float*)d_in[2];
    const float* g1  = (const float*)d_in[3];
    const float* be1 = (const float*)d_in[4];
    const float* m1  = (const float*)d_in[5];
    const float* v1  = (const float*)d_in[6];
    const float* w2  = (const float*)d_in[7];
    const float* b2  = (const float*)d_in[8];
    const float* g2  = (const float*)d_in[9];
    const float* be2 = (const float*)d_in[10];
    const float* m2  = (const float*)d_in[11];
    const float* v2  = (const float*)d_in[12];

    unsigned short* w1p = (unsigned short*)d_ws;
    unsigned short* w2p = w1p + 65536;
    float* cst = (float*)(w2p + 65536);   // scale1|bias1|scale2|bias2

    prep_kernel<<<256, 256, 0, stream>>>(w1, w2, b1, g1, be1, m1, v1,
                                         b2, g2, be2, m2, v2, w1p, w2p, cst);
    fused_kernel<<<2048, 256, 0, stream>>>(x, w1p, w2p, cst, (float*)d_out);
}